// Round 4
// baseline (876.065 us; speedup 1.0000x reference)
//
#include <hip/hip_runtime.h>
#include <hip/hip_bf16.h>

// ChebNet forward. R7 changes:
//  1. REMOVE cache gating (R6): rocprof proved ws is re-poisoned every
//     iteration (scatter ran full-cost each time) -- caching can never hit.
//  2. Deterministic counting-sort CSR build replaces the atomic ELL scatter.
//     Old scatter was transaction-rate bound: 1.6M random 8B writes (64B
//     sector RMW -> WRITE 99MB) + 1.6M global atomic round-trips = 122us.
//     New build: S1 per-chunk LDS hist over 512-row buckets; S2 single-block
//     matrix scan (exact offsets, no atomics); S3 LDS-staged binning with
//     coalesced per-bucket run flushes; S4 one block per bucket builds
//     compact CSR with LDS-only atomics, writes confined to a contiguous
//     ~64KB L2-resident region. Zero global atomics in the whole build.
//     Bonus: cw shrinks 38.4MB (ELL) -> 12.8MB (CSR) = smaller L3 footprint
//     for the SpMM gather layers.
//
// Carried: fc1 bf16 MFMA 16x16x32; 6-SpMM schedule (t2==t1 skip); poly folded
// at layers 3/5/7; tiered fallbacks (atomic ELL, compact-atomic CSR).

#define NFEAT 256
#define NHID  128
#define NCLS  40
#define ELLS  48
#define RPB   512      // rows per bucket (sort build)
#define RPB_SH 9
#define CH    8192     // edges per chunk (sort build)

typedef __hip_bfloat16 bf16;
typedef __attribute__((ext_vector_type(8))) short bf16x8;
typedef __attribute__((ext_vector_type(4))) float f32x4;

__device__ inline float2 load2b(const bf16* p) {
    __hip_bfloat162 v = *(const __hip_bfloat162*)p;
    return make_float2(__bfloat162float(v.x), __bfloat162float(v.y));
}
__device__ inline void store2b(bf16* p, float2 v) {
    __hip_bfloat162 o;
    o.x = __float2bfloat16(v.x);
    o.y = __float2bfloat16(v.y);
    *(__hip_bfloat162*)p = o;
}

// ================= counting-sort CSR build =================
// S1: per-chunk histogram over row buckets. cntT[b*NBLK + k] = count of
// chunk k's edges in bucket b.
__global__ __launch_bounds__(256) void s1_hist(
    const int* __restrict__ erow, int* __restrict__ cntT, int E, int NB, int NBLK) {
    __shared__ int lcnt[256];
    const int k = blockIdx.x, tid = threadIdx.x;
    for (int i = tid; i < NB; i += 256) lcnt[i] = 0;
    __syncthreads();
    int e0 = k * CH, e1 = min(e0 + CH, E);
    for (int e = e0 + tid; e < e1; e += 256)
        atomicAdd(&lcnt[erow[e] >> RPB_SH], 1);
    __syncthreads();
    for (int b = tid; b < NB; b += 256) cntT[b * NBLK + k] = lcnt[b];
}

// S2: exclusive scan of cntT in (bucket-major, chunk-minor) order -> offsT,
// plus bucket bases bbase[NB+1]. Single block, 1024 elems/iter.
__global__ __launch_bounds__(256) void s2_scan(
    const int* __restrict__ cntT, int* __restrict__ offsT, int* __restrict__ bbase,
    int NB, int NBLK, int E) {
    __shared__ int s_scan[256];
    __shared__ int s_run;
    const int tid = threadIdx.x;
    if (tid == 0) s_run = 0;
    __syncthreads();
    const int total = NB * NBLK;
    for (int base = 0; base < total; base += 1024) {
        int j0 = base + tid * 4;
        int v0 = (j0 + 0 < total) ? cntT[j0 + 0] : 0;
        int v1 = (j0 + 1 < total) ? cntT[j0 + 1] : 0;
        int v2 = (j0 + 2 < total) ? cntT[j0 + 2] : 0;
        int v3 = (j0 + 3 < total) ? cntT[j0 + 3] : 0;
        int tsum = v0 + v1 + v2 + v3;
        s_scan[tid] = tsum;
        __syncthreads();
        #pragma unroll
        for (int off = 1; off < 256; off <<= 1) {
            int t = (tid >= off) ? s_scan[tid - off] : 0;
            __syncthreads();
            s_scan[tid] += t;
            __syncthreads();
        }
        int incl = s_scan[tid];
        int excl = incl - tsum;
        int run = s_run;
        int chunk_total = s_scan[255];
        __syncthreads();
        int p = run + excl;
        int vv[4] = {v0, v1, v2, v3};
        int pre = 0;
        #pragma unroll
        for (int u = 0; u < 4; ++u) {
            int j = j0 + u;
            if (j < total) {
                offsT[j] = p + pre;
                if (j % NBLK == 0) bbase[j / NBLK] = p + pre;
            }
            pre += vv[u];
        }
        if (tid == 0) s_run = run + chunk_total;
        __syncthreads();
    }
    if (tid == 0) bbase[NB] = E;
}

// S3: re-read chunk edges, LDS-bin by bucket, flush coalesced per-bucket runs
// to the bucket-grouped edge buffer at exact offsets from S2.
__global__ __launch_bounds__(256) void s3_bin(
    const int* __restrict__ erow, const int* __restrict__ ecol,
    const float* __restrict__ ew, const int* __restrict__ offsT,
    int* __restrict__ bin_row, int2* __restrict__ bin_cw, int E, int NB, int NBLK) {
    __shared__ int lcnt[256], lbase[256], lcur[256], gadj[256];
    __shared__ int s_scan[256];
    __shared__ int srow[CH];
    __shared__ int2 scw[CH];
    const int k = blockIdx.x, tid = threadIdx.x;
    for (int i = tid; i < NB; i += 256) lcnt[i] = 0;
    __syncthreads();
    int e0 = k * CH, e1 = min(e0 + CH, E), cnt = e1 - e0;
    for (int e = e0 + tid; e < e1; e += 256)
        atomicAdd(&lcnt[erow[e] >> RPB_SH], 1);
    __syncthreads();
    int myv = (tid < NB) ? lcnt[tid] : 0;
    s_scan[tid] = myv;
    __syncthreads();
    #pragma unroll
    for (int off = 1; off < 256; off <<= 1) {
        int t = (tid >= off) ? s_scan[tid - off] : 0;
        __syncthreads();
        s_scan[tid] += t;
        __syncthreads();
    }
    int excl = s_scan[tid] - myv;
    if (tid < NB) {
        lbase[tid] = excl;
        lcur[tid] = excl;
        gadj[tid] = offsT[tid * NBLK + k] - excl;
    }
    __syncthreads();
    for (int e = e0 + tid; e < e1; e += 256) {
        int r = erow[e];
        int b = r >> RPB_SH;
        int s = atomicAdd(&lcur[b], 1);
        srow[s] = r;
        scw[s] = make_int2(ecol[e], __float_as_int(ew[e]));
    }
    __syncthreads();
    for (int i = tid; i < cnt; i += 256) {
        int r = srow[i];
        int b = r >> RPB_SH;
        int dst = gadj[b] + i;
        bin_row[dst] = r;
        bin_cw[dst] = scw[i];
    }
}

// S4: one block per bucket. LDS per-row counts -> scan -> compact CSR
// (deg, row_start, cw). All conflict resolution via LDS atomics; cw writes
// confined to the bucket's contiguous region.
__global__ __launch_bounds__(256) void s4_build(
    const int* __restrict__ bbase, const int* __restrict__ bin_row,
    const int2* __restrict__ bin_cw, int* __restrict__ deg,
    int* __restrict__ row_start, int2* __restrict__ cw, int N) {
    __shared__ int ldeg[RPB], lcur2[RPB];
    __shared__ int s_scan[256];
    const int b = blockIdx.x, tid = threadIdx.x;
    const int ebase = bbase[b], eend = bbase[b + 1];
    const int R0 = b << RPB_SH;
    ldeg[tid] = 0;
    ldeg[tid + 256] = 0;
    __syncthreads();
    for (int i = ebase + tid; i < eend; i += 256)
        atomicAdd(&ldeg[bin_row[i] - R0], 1);
    __syncthreads();
    int a0 = ldeg[2 * tid], a1 = ldeg[2 * tid + 1];
    int ps = a0 + a1;
    s_scan[tid] = ps;
    __syncthreads();
    #pragma unroll
    for (int off = 1; off < 256; off <<= 1) {
        int t = (tid >= off) ? s_scan[tid - off] : 0;
        __syncthreads();
        s_scan[tid] += t;
        __syncthreads();
    }
    int pexcl = s_scan[tid] - ps;
    lcur2[2 * tid] = pexcl;
    lcur2[2 * tid + 1] = pexcl + a0;
    __syncthreads();
    #pragma unroll
    for (int u = 0; u < 2; ++u) {
        int lr = 2 * tid + u;
        int r = R0 + lr;
        if (r < N) {
            deg[r] = ldeg[lr];
            row_start[r] = ebase + lcur2[lr];
        }
    }
    for (int i = ebase + tid; i < eend; i += 256) {
        int lr = bin_row[i] - R0;
        int s = atomicAdd(&lcur2[lr], 1);
        cw[ebase + s] = bin_cw[i];
    }
}

// ================= fallback builds =================
__global__ void zero_ints(int* __restrict__ p, int n) {
    int i = blockIdx.x * blockDim.x + threadIdx.x;
    if (i < n) p[i] = 0;
}

// Tier-2: atomic ELL scatter (R3 form).
__global__ void scatter_ell(const int* __restrict__ erow, const int* __restrict__ ecol,
                            const float* __restrict__ ew, int* __restrict__ deg,
                            int2* __restrict__ cw, int E) {
    int e = blockIdx.x * blockDim.x + threadIdx.x;
    if (e < E) {
        int r = erow[e];
        int p = atomicAdd(&deg[r], 1);
        if (p < ELLS)
            cw[(size_t)r * ELLS + p] = make_int2(ecol[e], __float_as_int(ew[e]));
    }
}

// Tier-3: compact-CSR via atomics.
__global__ void hist_kernel(const int* __restrict__ erow, int* __restrict__ deg, int E) {
    int e = blockIdx.x * blockDim.x + threadIdx.x;
    if (e < E) atomicAdd(&deg[erow[e]], 1);
}

__global__ void assign_starts(const int* __restrict__ deg, int* __restrict__ counter,
                              int* __restrict__ row_start, int* __restrict__ cursor, int N) {
    int r = blockIdx.x * blockDim.x + threadIdx.x;
    int lane = threadIdx.x & 63;
    int d = (r < N) ? deg[r] : 0;
    int x = d;
    #pragma unroll
    for (int off = 1; off < 64; off <<= 1) {
        int y = __shfl_up(x, off);
        if (lane >= off) x += y;
    }
    int base = 0;
    if (lane == 63) base = atomicAdd(counter, x);
    base = __shfl(base, 63);
    int start = base + (x - d);
    if (r < N) {
        row_start[r] = start;
        cursor[r] = start;
    }
}

__global__ void scatter_compact(const int* __restrict__ erow, const int* __restrict__ ecol,
                                const float* __restrict__ ew, int* __restrict__ cursor,
                                int2* __restrict__ cw, int E) {
    int e = blockIdx.x * blockDim.x + threadIdx.x;
    if (e < E) {
        int r = erow[e];
        int p = atomicAdd(&cursor[r], 1);
        cw[p] = make_int2(ecol[e], __float_as_int(ew[e]));
    }
}

// ================= FC1 via bf16 MFMA =================
__global__ __launch_bounds__(256) void fc1_mfma(
    const float* __restrict__ x, const float* __restrict__ W,
    const float* __restrict__ bias, bf16* __restrict__ t0, int n) {
    // Row stride 40 bf16 (80B): fragment b128 reads & 8B staging writes are
    // 2-way bank aliased (free on CDNA4).
    __shared__ __align__(16) bf16 As[128 * 40];
    __shared__ __align__(16) bf16 Bs[128 * 40];

    const int tid = threadIdx.x;
    const int wave = tid >> 6;
    const int lane = tid & 63;
    const int quad = lane >> 4;
    const int lm = lane & 15;
    const int block_row = blockIdx.x * 128;

    f32x4 acc[2][8];
    #pragma unroll
    for (int s = 0; s < 2; ++s)
        #pragma unroll
        for (int t = 0; t < 8; ++t)
            acc[s][t] = (f32x4){0.f, 0.f, 0.f, 0.f};

    float bcol[8];
    #pragma unroll
    for (int t = 0; t < 8; ++t) bcol[t] = bias[t * 16 + lm];

    for (int kc = 0; kc < NFEAT; kc += 32) {
        #pragma unroll
        for (int i = 0; i < 4; ++i) {
            int idx = tid + 256 * i;
            int row = idx >> 3;
            int c4 = idx & 7;
            int grow = block_row + row;
            float4 v = make_float4(0.f, 0.f, 0.f, 0.f);
            if (grow < n) v = *(const float4*)&x[(size_t)grow * NFEAT + kc + c4 * 4];
            __hip_bfloat162 lo2, hi2;
            lo2.x = __float2bfloat16(v.x); lo2.y = __float2bfloat16(v.y);
            hi2.x = __float2bfloat16(v.z); hi2.y = __float2bfloat16(v.w);
            *(__hip_bfloat162*)&As[row * 40 + c4 * 4] = lo2;
            *(__hip_bfloat162*)&As[row * 40 + c4 * 4 + 2] = hi2;
        }
        #pragma unroll
        for (int i = 0; i < 4; ++i) {
            int idx = tid + 256 * i;
            int nn = idx & 127;
            int k4 = idx >> 7;
            const float* wp = &W[(size_t)(kc + k4 * 4) * NHID + nn];
            float v0 = wp[0];
            float v1 = wp[NHID];
            float v2 = wp[2 * NHID];
            float v3 = wp[3 * NHID];
            __hip_bfloat162 lo2, hi2;
            lo2.x = __float2bfloat16(v0); lo2.y = __float2bfloat16(v1);
            hi2.x = __float2bfloat16(v2); hi2.y = __float2bfloat16(v3);
            *(__hip_bfloat162*)&Bs[nn * 40 + k4 * 4] = lo2;
            *(__hip_bfloat162*)&Bs[nn * 40 + k4 * 4 + 2] = hi2;
        }
        __syncthreads();

        bf16x8 af0 = *(const bf16x8*)&As[(wave * 32 + lm) * 40 + quad * 8];
        bf16x8 af1 = *(const bf16x8*)&As[(wave * 32 + 16 + lm) * 40 + quad * 8];
        #pragma unroll
        for (int t = 0; t < 8; ++t) {
            bf16x8 bf = *(const bf16x8*)&Bs[(t * 16 + lm) * 40 + quad * 8];
            acc[0][t] = __builtin_amdgcn_mfma_f32_16x16x32_bf16(af0, bf, acc[0][t], 0, 0, 0);
            acc[1][t] = __builtin_amdgcn_mfma_f32_16x16x32_bf16(af1, bf, acc[1][t], 0, 0, 0);
        }
        __syncthreads();
    }

    #pragma unroll
    for (int s = 0; s < 2; ++s) {
        #pragma unroll
        for (int r = 0; r < 4; ++r) {
            int grow = block_row + wave * 32 + s * 16 + quad * 4 + r;
            if (grow >= n) continue;
            bf16* orow = t0 + (size_t)grow * NHID + lm;
            #pragma unroll
            for (int t = 0; t < 8; ++t) {
                float v = fmaxf(acc[s][t][r] + bcol[t], 0.f);
                orow[t * 16] = __float2bfloat16(v);
            }
        }
    }
}

// ================= SpMM + Chebyshev + poly =================
// Schedule (t2==t1 skipped):
//   L1: t1 = L@t0                                 FIRST,  PMODE0
//   L3: t3 = 2*L@t1 - t0; poly = th0*t0+(th1+th2)*t1+th3*t3   PMODE1
//   L4: t4 = 2*L@t3 - t1                          PMODE0
//   L5: t5 = 2*L@t4 - t3; poly += th4*t4+th5*t5   PMODE2
//   L6: t6 = 2*L@t5 - t4                          PMODE0
//   L7: poly += th6*t6+th7*t7; no t-store         PMODE3
template <bool FIRST, int PMODE>
__global__ __launch_bounds__(256) void spmm_cheb(
    const int* __restrict__ row_start, const int* __restrict__ deg,
    const int2* __restrict__ cw,
    const bf16* __restrict__ tprev, const bf16* __restrict__ tsub,
    bf16* __restrict__ tout, float* __restrict__ poly,
    const float* __restrict__ thetas, int layer, int ell_stride, int n) {
    int lane = threadIdx.x & 63;
    int wid = (int)((blockIdx.x * (unsigned)blockDim.x + threadIdx.x) >> 6);
    if (wid >= n) return;
    int start = ell_stride ? wid * ell_stride : row_start[wid];
    int d = deg[wid];
    const int2* ep = cw + start;
    const int lo = 2 * lane;

    float2 acc = make_float2(0.f, 0.f);
    int j = 0;
    for (; j + 8 <= d; j += 8) {
        int2 e[8];
        #pragma unroll
        for (int u = 0; u < 8; ++u) e[u] = ep[j + u];
        float2 tv[8];
        #pragma unroll
        for (int u = 0; u < 8; ++u) tv[u] = load2b(tprev + (size_t)e[u].x * NHID + lo);
        #pragma unroll
        for (int u = 0; u < 8; ++u) {
            float w = __int_as_float(e[u].y);
            acc.x = fmaf(w, tv[u].x, acc.x);
            acc.y = fmaf(w, tv[u].y, acc.y);
        }
    }
    for (; j < d; ++j) {
        int2 e = ep[j];
        float w = __int_as_float(e.y);
        float2 tv = load2b(tprev + (size_t)e.x * NHID + lo);
        acc.x = fmaf(w, tv.x, acc.x);
        acc.y = fmaf(w, tv.y, acc.y);
    }

    size_t o = (size_t)wid * NHID + lo;
    float2 res, pv;
    if constexpr (FIRST) {
        res = acc;
    } else {
        pv = load2b(tsub + o);
        res = make_float2(2.f * acc.x - pv.x, 2.f * acc.y - pv.y);
    }
    if constexpr (PMODE != 3) store2b(tout + o, res);

    if constexpr (PMODE == 1) {
        float th0 = thetas[0], th12 = thetas[1] + thetas[2], th3 = thetas[3];
        float2 tpv = load2b(tprev + o);
        float2 p;
        p.x = th0 * pv.x + th12 * tpv.x + th3 * res.x;
        p.y = th0 * pv.y + th12 * tpv.y + th3 * res.y;
        *(float2*)&poly[o] = p;
    } else if constexpr (PMODE == 2 || PMODE == 3) {
        float tha = thetas[layer - 1], thb = thetas[layer];
        float2 tpv = load2b(tprev + o);
        float2 p = *(float2*)&poly[o];
        p.x += tha * tpv.x + thb * res.x;
        p.y += tha * tpv.y + thb * res.y;
        *(float2*)&poly[o] = p;
    }
}

// ================= FC2 + log_softmax =================
__global__ __launch_bounds__(256) void fc2_softmax(
    const float* __restrict__ poly, const float* __restrict__ w2,
    const float* __restrict__ b2, float* __restrict__ out, int n) {
    int row = blockIdx.x * 256 + threadIdx.x;
    if (row >= n) return;

    float acc[NCLS];
    #pragma unroll
    for (int c = 0; c < NCLS; ++c) acc[c] = b2[c];

    const float* pr = poly + (size_t)row * NHID;
    #pragma unroll 1
    for (int k = 0; k < NHID; k += 4) {
        float4 p = *(const float4*)&pr[k];
        const float* wr = w2 + (size_t)k * NCLS;
        #pragma unroll
        for (int c = 0; c < NCLS; ++c) {
            acc[c] = fmaf(p.x, wr[c], acc[c]);
            acc[c] = fmaf(p.y, wr[NCLS + c], acc[c]);
            acc[c] = fmaf(p.z, wr[2 * NCLS + c], acc[c]);
            acc[c] = fmaf(p.w, wr[3 * NCLS + c], acc[c]);
        }
    }

    float m = acc[0];
    #pragma unroll
    for (int c = 1; c < NCLS; ++c) m = fmaxf(m, acc[c]);
    float s = 0.f;
    #pragma unroll
    for (int c = 0; c < NCLS; ++c) s += __expf(acc[c] - m);
    float lse = m + __logf(s);

    float* orow = out + (size_t)row * NCLS;
    #pragma unroll
    for (int c = 0; c < NCLS; c += 4) {
        float4 v = make_float4(acc[c] - lse, acc[c + 1] - lse,
                               acc[c + 2] - lse, acc[c + 3] - lse);
        *(float4*)&orow[c] = v;
    }
}

// ================= orchestration =================
static void run_pipeline(const float* x, const float* w1, const float* b1,
                         const float* w2, const float* b2, const float* thetas,
                         float* out, int N, int E,
                         const int* row_start, const int* deg, const int2* cw,
                         int ell_stride, float* poly, bf16* tX, bf16* tY, bf16* tZ,
                         hipStream_t stream) {
    fc1_mfma<<<(N + 127) / 128, 256, 0, stream>>>(x, w1, b1, tX, N);

    int spmm_blocks = (int)(((size_t)N * 64 + 255) / 256);
    spmm_cheb<true, 0><<<spmm_blocks, 256, 0, stream>>>(
        row_start, deg, cw, tX, (const bf16*)nullptr, tY, poly, thetas, 1, ell_stride, N);
    spmm_cheb<false, 1><<<spmm_blocks, 256, 0, stream>>>(
        row_start, deg, cw, tY, tX, tZ, poly, thetas, 3, ell_stride, N);
    spmm_cheb<false, 0><<<spmm_blocks, 256, 0, stream>>>(
        row_start, deg, cw, tZ, tY, tX, poly, thetas, 4, ell_stride, N);
    spmm_cheb<false, 2><<<spmm_blocks, 256, 0, stream>>>(
        row_start, deg, cw, tX, tZ, tY, poly, thetas, 5, ell_stride, N);
    spmm_cheb<false, 0><<<spmm_blocks, 256, 0, stream>>>(
        row_start, deg, cw, tY, tX, tZ, poly, thetas, 6, ell_stride, N);
    spmm_cheb<false, 3><<<spmm_blocks, 256, 0, stream>>>(
        row_start, deg, cw, tZ, tY, (bf16*)nullptr, poly, thetas, 7, ell_stride, N);

    fc2_softmax<<<(N + 255) / 256, 256, 0, stream>>>(poly, w2, b2, out, N);
}

extern "C" void kernel_launch(void* const* d_in, const int* in_sizes, int n_in,
                              void* d_out, int out_size, void* d_ws, size_t ws_size,
                              hipStream_t stream) {
    const float* x      = (const float*)d_in[0];
    const int*   erow   = (const int*)d_in[1];
    const int*   ecol   = (const int*)d_in[2];
    const float* ew     = (const float*)d_in[3];
    const float* w1     = (const float*)d_in[4];
    const float* b1     = (const float*)d_in[5];
    const float* w2     = (const float*)d_in[6];
    const float* b2     = (const float*)d_in[7];
    const float* thetas = (const float*)d_in[8];
    float* out = (float*)d_out;

    const int N = in_sizes[0] / NFEAT;
    const int E = in_sizes[1];

    const int NB   = (N + RPB - 1) >> RPB_SH;   // row buckets
    const int NBLK = (E + CH - 1) / CH;          // edge chunks

    char* ws = (char*)d_ws;
    size_t off = 0;
    auto alloc = [&](size_t bytes) -> void* {
        off = (off + 255) & ~(size_t)255;
        void* p = ws + off;
        off += bytes;
        return p;
    };

    // Shared tail: poly + 3 bf16 t buffers.
    size_t tail = (size_t)N * NHID * 4 + 3 * ((size_t)N * NHID * 2 + 256) + 4096;

    size_t need_sort = 2 * (size_t)NB * NBLK * 4 + (size_t)(NB + 1) * 4 +
                       (size_t)E * 4 + (size_t)E * 8 +           // bin_row, bin_cw
                       2 * (size_t)N * 4 +                        // deg, row_start
                       (size_t)E * 8 + tail + 8192;               // cw compact
    size_t need_ell  = (size_t)N * 4 + (size_t)N * ELLS * 8 + tail + 8192;
    size_t need_comp = (size_t)(N + 1) * 4 + 2 * (size_t)N * 4 +
                       (size_t)E * 8 + tail + 8192;

    if (NB <= 256 && need_sort <= ws_size) {
        // -------- primary: deterministic counting-sort CSR --------
        int*  cntT      = (int*)alloc((size_t)NB * NBLK * 4);
        int*  offsT     = (int*)alloc((size_t)NB * NBLK * 4);
        int*  bbase     = (int*)alloc((size_t)(NB + 1) * 4);
        int*  bin_row   = (int*)alloc((size_t)E * 4);
        int2* bin_cw    = (int2*)alloc((size_t)E * 8);
        int*  deg       = (int*)alloc((size_t)N * 4);
        int*  row_start = (int*)alloc((size_t)N * 4);
        int2* cw        = (int2*)alloc((size_t)E * 8);
        float* poly = (float*)alloc((size_t)N * NHID * 4);
        bf16*  tX   = (bf16*)alloc((size_t)N * NHID * 2);
        bf16*  tY   = (bf16*)alloc((size_t)N * NHID * 2);
        bf16*  tZ   = (bf16*)alloc((size_t)N * NHID * 2);

        s1_hist<<<NBLK, 256, 0, stream>>>(erow, cntT, E, NB, NBLK);
        s2_scan<<<1, 256, 0, stream>>>(cntT, offsT, bbase, NB, NBLK, E);
        s3_bin<<<NBLK, 256, 0, stream>>>(erow, ecol, ew, offsT, bin_row, bin_cw, E, NB, NBLK);
        s4_build<<<NB, 256, 0, stream>>>(bbase, bin_row, bin_cw, deg, row_start, cw, N);
        run_pipeline(x, w1, b1, w2, b2, thetas, out, N, E,
                     row_start, deg, cw, 0, poly, tX, tY, tZ, stream);
    } else if (need_ell <= ws_size) {
        // -------- tier-2: atomic ELL --------
        int*   deg  = (int*)alloc((size_t)N * 4);
        int2*  cw   = (int2*)alloc((size_t)N * ELLS * 8);
        float* poly = (float*)alloc((size_t)N * NHID * 4);
        bf16*  tX   = (bf16*)alloc((size_t)N * NHID * 2);
        bf16*  tY   = (bf16*)alloc((size_t)N * NHID * 2);
        bf16*  tZ   = (bf16*)alloc((size_t)N * NHID * 2);

        zero_ints<<<(N + 255) / 256, 256, 0, stream>>>(deg, N);
        scatter_ell<<<(E + 255) / 256, 256, 0, stream>>>(erow, ecol, ew, deg, cw, E);
        run_pipeline(x, w1, b1, w2, b2, thetas, out, N, E,
                     nullptr, deg, cw, ELLS, poly, tX, tY, tZ, stream);
    } else {
        // -------- tier-3: compact CSR via atomics --------
        int*   deg       = (int*)alloc((size_t)(N + 1) * 4);
        int*   counter   = deg + N;
        int*   row_start = (int*)alloc((size_t)N * 4);
        int*   cursor    = (int*)alloc((size_t)N * 4);
        int2*  cw        = (int2*)alloc((size_t)E * 8);
        float* poly      = (float*)alloc((size_t)N * NHID * 4);
        bf16*  tX        = (bf16*)alloc((size_t)N * NHID * 2);
        bf16*  tY        = (bf16*)alloc((size_t)N * NHID * 2);
        bf16*  tZ        = (bf16*)alloc((size_t)N * NHID * 2);

        zero_ints<<<(N + 1 + 255) / 256, 256, 0, stream>>>(deg, N + 1);
        hist_kernel<<<(E + 255) / 256, 256, 0, stream>>>(erow, deg, E);
        assign_starts<<<(N + 255) / 256, 256, 0, stream>>>(deg, counter, row_start, cursor, N);
        scatter_compact<<<(E + 255) / 256, 256, 0, stream>>>(erow, ecol, ew, cursor, cw, E);
        run_pipeline(x, w1, b1, w2, b2, thetas, out, N, E,
                     row_start, deg, cw, 0, poly, tX, tY, tZ, stream);
    }
}

// Round 5
// 866.946 us; speedup vs baseline: 1.0105x; 1.0105x over previous
//
#include <hip/hip_runtime.h>
#include <hip/hip_bf16.h>

// ChebNet forward. R8 changes (build parallelization; R7 post-mortem showed
// the counting-sort build cost ~300us):
//  1. s2 single-block scan (38 chunks x ~16 barriers serialized on ONE CU)
//     replaced by hierarchical scan: s2_bases (1 block, 512 thr: per-bucket
//     totals + one 512-wide scan) + s2_offsets (NB blocks, one 256-chunk
//     scan each).
//  2. RPB 512->256, CH 8192->4096: NB/NBLK 196->391. S3 LDS 101KB->57KB
//     (2 blocks/CU), S4 per-block edge count halved -> both get ~2-4x more
//     resident waves. Build predicted ~300 -> ~40us.
//
// Carried: compact-CSR counting-sort build (zero global atomics); fc1 bf16
// MFMA 16x16x32; 6-SpMM schedule (t2==t1 skip); poly folded at layers 3/5/7;
// tiered fallbacks (atomic ELL, compact-atomic CSR).

#define NFEAT 256
#define NHID  128
#define NCLS  40
#define ELLS  48
#define RPB   256      // rows per bucket (sort build)
#define RPB_SH 8
#define CH    4096     // edges per chunk (sort build)
#define NBMAX 512

typedef __hip_bfloat16 bf16;
typedef __attribute__((ext_vector_type(8))) short bf16x8;
typedef __attribute__((ext_vector_type(4))) float f32x4;

__device__ inline float2 load2b(const bf16* p) {
    __hip_bfloat162 v = *(const __hip_bfloat162*)p;
    return make_float2(__bfloat162float(v.x), __bfloat162float(v.y));
}
__device__ inline void store2b(bf16* p, float2 v) {
    __hip_bfloat162 o;
    o.x = __float2bfloat16(v.x);
    o.y = __float2bfloat16(v.y);
    *(__hip_bfloat162*)p = o;
}

// ================= counting-sort CSR build =================
// S1: per-chunk histogram over row buckets. cntT[b*NBLK + k] = count of
// chunk k's edges in bucket b.
__global__ __launch_bounds__(256) void s1_hist(
    const int* __restrict__ erow, int* __restrict__ cntT, int E, int NB, int NBLK) {
    __shared__ int lcnt[NBMAX];
    const int k = blockIdx.x, tid = threadIdx.x;
    for (int i = tid; i < NB; i += 256) lcnt[i] = 0;
    __syncthreads();
    int e0 = k * CH, e1 = min(e0 + CH, E);
    for (int e = e0 + tid; e < e1; e += 256)
        atomicAdd(&lcnt[erow[e] >> RPB_SH], 1);
    __syncthreads();
    for (int b = tid; b < NB; b += 256) cntT[b * NBLK + k] = lcnt[b];
}

// S2a: per-bucket totals + exclusive scan -> bucket bases. One block, 512 thr.
__global__ __launch_bounds__(512) void s2_bases(
    const int* __restrict__ cntT, int* __restrict__ bbase, int NB, int NBLK, int E) {
    __shared__ int s_scan[512];
    const int tid = threadIdx.x;
    int sum = 0;
    if (tid < NB) {
        const int* p = cntT + (size_t)tid * NBLK;
        for (int k = 0; k < NBLK; ++k) sum += p[k];
    }
    s_scan[tid] = sum;
    __syncthreads();
    #pragma unroll
    for (int off = 1; off < 512; off <<= 1) {
        int t = (tid >= off) ? s_scan[tid - off] : 0;
        __syncthreads();
        s_scan[tid] += t;
        __syncthreads();
    }
    if (tid < NB) bbase[tid] = s_scan[tid] - sum;
    if (tid == 0) bbase[NB] = E;
}

// S2b: per-bucket exclusive scan over its chunk counts -> exact offsets.
// Grid = NB blocks.
__global__ __launch_bounds__(256) void s2_offsets(
    const int* __restrict__ cntT, const int* __restrict__ bbase,
    int* __restrict__ offsT, int NBLK) {
    __shared__ int s_scan[256];
    const int b = blockIdx.x, tid = threadIdx.x;
    int run = bbase[b];
    for (int base = 0; base < NBLK; base += 256) {
        int k = base + tid;
        int v = (k < NBLK) ? cntT[(size_t)b * NBLK + k] : 0;
        s_scan[tid] = v;
        __syncthreads();
        #pragma unroll
        for (int off = 1; off < 256; off <<= 1) {
            int t = (tid >= off) ? s_scan[tid - off] : 0;
            __syncthreads();
            s_scan[tid] += t;
            __syncthreads();
        }
        int incl = s_scan[tid];
        if (k < NBLK) offsT[(size_t)b * NBLK + k] = run + incl - v;
        int tot = s_scan[255];
        __syncthreads();
        run += tot;
    }
}

// S3: re-read chunk edges, LDS-bin by bucket, flush coalesced per-bucket runs
// to the bucket-grouped edge buffer at exact offsets from S2.
__global__ __launch_bounds__(256) void s3_bin(
    const int* __restrict__ erow, const int* __restrict__ ecol,
    const float* __restrict__ ew, const int* __restrict__ offsT,
    int* __restrict__ bin_row, int2* __restrict__ bin_cw, int E, int NB, int NBLK) {
    __shared__ int lcnt[NBMAX], lcur[NBMAX], gadj[NBMAX];
    __shared__ int s_scan[256];
    __shared__ int srow[CH];
    __shared__ int2 scw[CH];
    const int k = blockIdx.x, tid = threadIdx.x;
    for (int i = tid; i < NB; i += 256) lcnt[i] = 0;
    __syncthreads();
    int e0 = k * CH, e1 = min(e0 + CH, E), cnt = e1 - e0;
    for (int e = e0 + tid; e < e1; e += 256)
        atomicAdd(&lcnt[erow[e] >> RPB_SH], 1);
    __syncthreads();
    // bucket scan, 2 entries per thread (NB <= 512)
    int a0 = (2 * tid < NB) ? lcnt[2 * tid] : 0;
    int a1 = (2 * tid + 1 < NB) ? lcnt[2 * tid + 1] : 0;
    int ps = a0 + a1;
    s_scan[tid] = ps;
    __syncthreads();
    #pragma unroll
    for (int off = 1; off < 256; off <<= 1) {
        int t = (tid >= off) ? s_scan[tid - off] : 0;
        __syncthreads();
        s_scan[tid] += t;
        __syncthreads();
    }
    int excl = s_scan[tid] - ps;
    if (2 * tid < NB) {
        lcur[2 * tid] = excl;
        gadj[2 * tid] = offsT[(size_t)(2 * tid) * NBLK + k] - excl;
    }
    if (2 * tid + 1 < NB) {
        lcur[2 * tid + 1] = excl + a0;
        gadj[2 * tid + 1] = offsT[(size_t)(2 * tid + 1) * NBLK + k] - (excl + a0);
    }
    __syncthreads();
    for (int e = e0 + tid; e < e1; e += 256) {
        int r = erow[e];
        int b = r >> RPB_SH;
        int s = atomicAdd(&lcur[b], 1);
        srow[s] = r;
        scw[s] = make_int2(ecol[e], __float_as_int(ew[e]));
    }
    __syncthreads();
    for (int i = tid; i < cnt; i += 256) {
        int r = srow[i];
        int b = r >> RPB_SH;
        int dst = gadj[b] + i;
        bin_row[dst] = r;
        bin_cw[dst] = scw[i];
    }
}

// S4: one block per bucket (256 rows). LDS per-row counts -> scan -> compact
// CSR (deg, row_start, cw). All conflict resolution via LDS atomics; cw
// writes confined to the bucket's contiguous region.
__global__ __launch_bounds__(256) void s4_build(
    const int* __restrict__ bbase, const int* __restrict__ bin_row,
    const int2* __restrict__ bin_cw, int* __restrict__ deg,
    int* __restrict__ row_start, int2* __restrict__ cw, int N) {
    __shared__ int ldeg[RPB], lcur2[RPB];
    __shared__ int s_scan[256];
    const int b = blockIdx.x, tid = threadIdx.x;
    const int ebase = bbase[b], eend = bbase[b + 1];
    const int R0 = b << RPB_SH;
    ldeg[tid] = 0;
    __syncthreads();
    for (int i = ebase + tid; i < eend; i += 256)
        atomicAdd(&ldeg[bin_row[i] - R0], 1);
    __syncthreads();
    int d = ldeg[tid];
    s_scan[tid] = d;
    __syncthreads();
    #pragma unroll
    for (int off = 1; off < 256; off <<= 1) {
        int t = (tid >= off) ? s_scan[tid - off] : 0;
        __syncthreads();
        s_scan[tid] += t;
        __syncthreads();
    }
    int excl = s_scan[tid] - d;
    lcur2[tid] = excl;
    int r = R0 + tid;
    if (r < N) {
        deg[r] = d;
        row_start[r] = ebase + excl;
    }
    __syncthreads();
    for (int i = ebase + tid; i < eend; i += 256) {
        int lr = bin_row[i] - R0;
        int s = atomicAdd(&lcur2[lr], 1);
        cw[ebase + s] = bin_cw[i];
    }
}

// ================= fallback builds =================
__global__ void zero_ints(int* __restrict__ p, int n) {
    int i = blockIdx.x * blockDim.x + threadIdx.x;
    if (i < n) p[i] = 0;
}

// Tier-2: atomic ELL scatter (R3 form).
__global__ void scatter_ell(const int* __restrict__ erow, const int* __restrict__ ecol,
                            const float* __restrict__ ew, int* __restrict__ deg,
                            int2* __restrict__ cw, int E) {
    int e = blockIdx.x * blockDim.x + threadIdx.x;
    if (e < E) {
        int r = erow[e];
        int p = atomicAdd(&deg[r], 1);
        if (p < ELLS)
            cw[(size_t)r * ELLS + p] = make_int2(ecol[e], __float_as_int(ew[e]));
    }
}

// Tier-3: compact-CSR via atomics.
__global__ void hist_kernel(const int* __restrict__ erow, int* __restrict__ deg, int E) {
    int e = blockIdx.x * blockDim.x + threadIdx.x;
    if (e < E) atomicAdd(&deg[erow[e]], 1);
}

__global__ void assign_starts(const int* __restrict__ deg, int* __restrict__ counter,
                              int* __restrict__ row_start, int* __restrict__ cursor, int N) {
    int r = blockIdx.x * blockDim.x + threadIdx.x;
    int lane = threadIdx.x & 63;
    int d = (r < N) ? deg[r] : 0;
    int x = d;
    #pragma unroll
    for (int off = 1; off < 64; off <<= 1) {
        int y = __shfl_up(x, off);
        if (lane >= off) x += y;
    }
    int base = 0;
    if (lane == 63) base = atomicAdd(counter, x);
    base = __shfl(base, 63);
    int start = base + (x - d);
    if (r < N) {
        row_start[r] = start;
        cursor[r] = start;
    }
}

__global__ void scatter_compact(const int* __restrict__ erow, const int* __restrict__ ecol,
                                const float* __restrict__ ew, int* __restrict__ cursor,
                                int2* __restrict__ cw, int E) {
    int e = blockIdx.x * blockDim.x + threadIdx.x;
    if (e < E) {
        int r = erow[e];
        int p = atomicAdd(&cursor[r], 1);
        cw[p] = make_int2(ecol[e], __float_as_int(ew[e]));
    }
}

// ================= FC1 via bf16 MFMA =================
__global__ __launch_bounds__(256) void fc1_mfma(
    const float* __restrict__ x, const float* __restrict__ W,
    const float* __restrict__ bias, bf16* __restrict__ t0, int n) {
    // Row stride 40 bf16 (80B): fragment b128 reads & 8B staging writes are
    // 2-way bank aliased (free on CDNA4).
    __shared__ __align__(16) bf16 As[128 * 40];
    __shared__ __align__(16) bf16 Bs[128 * 40];

    const int tid = threadIdx.x;
    const int wave = tid >> 6;
    const int lane = tid & 63;
    const int quad = lane >> 4;
    const int lm = lane & 15;
    const int block_row = blockIdx.x * 128;

    f32x4 acc[2][8];
    #pragma unroll
    for (int s = 0; s < 2; ++s)
        #pragma unroll
        for (int t = 0; t < 8; ++t)
            acc[s][t] = (f32x4){0.f, 0.f, 0.f, 0.f};

    float bcol[8];
    #pragma unroll
    for (int t = 0; t < 8; ++t) bcol[t] = bias[t * 16 + lm];

    for (int kc = 0; kc < NFEAT; kc += 32) {
        #pragma unroll
        for (int i = 0; i < 4; ++i) {
            int idx = tid + 256 * i;
            int row = idx >> 3;
            int c4 = idx & 7;
            int grow = block_row + row;
            float4 v = make_float4(0.f, 0.f, 0.f, 0.f);
            if (grow < n) v = *(const float4*)&x[(size_t)grow * NFEAT + kc + c4 * 4];
            __hip_bfloat162 lo2, hi2;
            lo2.x = __float2bfloat16(v.x); lo2.y = __float2bfloat16(v.y);
            hi2.x = __float2bfloat16(v.z); hi2.y = __float2bfloat16(v.w);
            *(__hip_bfloat162*)&As[row * 40 + c4 * 4] = lo2;
            *(__hip_bfloat162*)&As[row * 40 + c4 * 4 + 2] = hi2;
        }
        #pragma unroll
        for (int i = 0; i < 4; ++i) {
            int idx = tid + 256 * i;
            int nn = idx & 127;
            int k4 = idx >> 7;
            const float* wp = &W[(size_t)(kc + k4 * 4) * NHID + nn];
            float v0 = wp[0];
            float v1 = wp[NHID];
            float v2 = wp[2 * NHID];
            float v3 = wp[3 * NHID];
            __hip_bfloat162 lo2, hi2;
            lo2.x = __float2bfloat16(v0); lo2.y = __float2bfloat16(v1);
            hi2.x = __float2bfloat16(v2); hi2.y = __float2bfloat16(v3);
            *(__hip_bfloat162*)&Bs[nn * 40 + k4 * 4] = lo2;
            *(__hip_bfloat162*)&Bs[nn * 40 + k4 * 4 + 2] = hi2;
        }
        __syncthreads();

        bf16x8 af0 = *(const bf16x8*)&As[(wave * 32 + lm) * 40 + quad * 8];
        bf16x8 af1 = *(const bf16x8*)&As[(wave * 32 + 16 + lm) * 40 + quad * 8];
        #pragma unroll
        for (int t = 0; t < 8; ++t) {
            bf16x8 bf = *(const bf16x8*)&Bs[(t * 16 + lm) * 40 + quad * 8];
            acc[0][t] = __builtin_amdgcn_mfma_f32_16x16x32_bf16(af0, bf, acc[0][t], 0, 0, 0);
            acc[1][t] = __builtin_amdgcn_mfma_f32_16x16x32_bf16(af1, bf, acc[1][t], 0, 0, 0);
        }
        __syncthreads();
    }

    #pragma unroll
    for (int s = 0; s < 2; ++s) {
        #pragma unroll
        for (int r = 0; r < 4; ++r) {
            int grow = block_row + wave * 32 + s * 16 + quad * 4 + r;
            if (grow >= n) continue;
            bf16* orow = t0 + (size_t)grow * NHID + lm;
            #pragma unroll
            for (int t = 0; t < 8; ++t) {
                float v = fmaxf(acc[s][t][r] + bcol[t], 0.f);
                orow[t * 16] = __float2bfloat16(v);
            }
        }
    }
}

// ================= SpMM + Chebyshev + poly =================
// Schedule (t2==t1 skipped):
//   L1: t1 = L@t0                                 FIRST,  PMODE0
//   L3: t3 = 2*L@t1 - t0; poly = th0*t0+(th1+th2)*t1+th3*t3   PMODE1
//   L4: t4 = 2*L@t3 - t1                          PMODE0
//   L5: t5 = 2*L@t4 - t3; poly += th4*t4+th5*t5   PMODE2
//   L6: t6 = 2*L@t5 - t4                          PMODE0
//   L7: poly += th6*t6+th7*t7; no t-store         PMODE3
template <bool FIRST, int PMODE>
__global__ __launch_bounds__(256) void spmm_cheb(
    const int* __restrict__ row_start, const int* __restrict__ deg,
    const int2* __restrict__ cw,
    const bf16* __restrict__ tprev, const bf16* __restrict__ tsub,
    bf16* __restrict__ tout, float* __restrict__ poly,
    const float* __restrict__ thetas, int layer, int ell_stride, int n) {
    int lane = threadIdx.x & 63;
    int wid = (int)((blockIdx.x * (unsigned)blockDim.x + threadIdx.x) >> 6);
    if (wid >= n) return;
    int start = ell_stride ? wid * ell_stride : row_start[wid];
    int d = deg[wid];
    const int2* ep = cw + start;
    const int lo = 2 * lane;

    float2 acc = make_float2(0.f, 0.f);
    int j = 0;
    for (; j + 8 <= d; j += 8) {
        int2 e[8];
        #pragma unroll
        for (int u = 0; u < 8; ++u) e[u] = ep[j + u];
        float2 tv[8];
        #pragma unroll
        for (int u = 0; u < 8; ++u) tv[u] = load2b(tprev + (size_t)e[u].x * NHID + lo);
        #pragma unroll
        for (int u = 0; u < 8; ++u) {
            float w = __int_as_float(e[u].y);
            acc.x = fmaf(w, tv[u].x, acc.x);
            acc.y = fmaf(w, tv[u].y, acc.y);
        }
    }
    for (; j < d; ++j) {
        int2 e = ep[j];
        float w = __int_as_float(e.y);
        float2 tv = load2b(tprev + (size_t)e.x * NHID + lo);
        acc.x = fmaf(w, tv.x, acc.x);
        acc.y = fmaf(w, tv.y, acc.y);
    }

    size_t o = (size_t)wid * NHID + lo;
    float2 res, pv;
    if constexpr (FIRST) {
        res = acc;
    } else {
        pv = load2b(tsub + o);
        res = make_float2(2.f * acc.x - pv.x, 2.f * acc.y - pv.y);
    }
    if constexpr (PMODE != 3) store2b(tout + o, res);

    if constexpr (PMODE == 1) {
        float th0 = thetas[0], th12 = thetas[1] + thetas[2], th3 = thetas[3];
        float2 tpv = load2b(tprev + o);
        float2 p;
        p.x = th0 * pv.x + th12 * tpv.x + th3 * res.x;
        p.y = th0 * pv.y + th12 * tpv.y + th3 * res.y;
        *(float2*)&poly[o] = p;
    } else if constexpr (PMODE == 2 || PMODE == 3) {
        float tha = thetas[layer - 1], thb = thetas[layer];
        float2 tpv = load2b(tprev + o);
        float2 p = *(float2*)&poly[o];
        p.x += tha * tpv.x + thb * res.x;
        p.y += tha * tpv.y + thb * res.y;
        *(float2*)&poly[o] = p;
    }
}

// ================= FC2 + log_softmax =================
__global__ __launch_bounds__(256) void fc2_softmax(
    const float* __restrict__ poly, const float* __restrict__ w2,
    const float* __restrict__ b2, float* __restrict__ out, int n) {
    int row = blockIdx.x * 256 + threadIdx.x;
    if (row >= n) return;

    float acc[NCLS];
    #pragma unroll
    for (int c = 0; c < NCLS; ++c) acc[c] = b2[c];

    const float* pr = poly + (size_t)row * NHID;
    #pragma unroll 1
    for (int k = 0; k < NHID; k += 4) {
        float4 p = *(const float4*)&pr[k];
        const float* wr = w2 + (size_t)k * NCLS;
        #pragma unroll
        for (int c = 0; c < NCLS; ++c) {
            acc[c] = fmaf(p.x, wr[c], acc[c]);
            acc[c] = fmaf(p.y, wr[NCLS + c], acc[c]);
            acc[c] = fmaf(p.z, wr[2 * NCLS + c], acc[c]);
            acc[c] = fmaf(p.w, wr[3 * NCLS + c], acc[c]);
        }
    }

    float m = acc[0];
    #pragma unroll
    for (int c = 1; c < NCLS; ++c) m = fmaxf(m, acc[c]);
    float s = 0.f;
    #pragma unroll
    for (int c = 0; c < NCLS; ++c) s += __expf(acc[c] - m);
    float lse = m + __logf(s);

    float* orow = out + (size_t)row * NCLS;
    #pragma unroll
    for (int c = 0; c < NCLS; c += 4) {
        float4 v = make_float4(acc[c] - lse, acc[c + 1] - lse,
                               acc[c + 2] - lse, acc[c + 3] - lse);
        *(float4*)&orow[c] = v;
    }
}

// ================= orchestration =================
static void run_pipeline(const float* x, const float* w1, const float* b1,
                         const float* w2, const float* b2, const float* thetas,
                         float* out, int N, int E,
                         const int* row_start, const int* deg, const int2* cw,
                         int ell_stride, float* poly, bf16* tX, bf16* tY, bf16* tZ,
                         hipStream_t stream) {
    fc1_mfma<<<(N + 127) / 128, 256, 0, stream>>>(x, w1, b1, tX, N);

    int spmm_blocks = (int)(((size_t)N * 64 + 255) / 256);
    spmm_cheb<true, 0><<<spmm_blocks, 256, 0, stream>>>(
        row_start, deg, cw, tX, (const bf16*)nullptr, tY, poly, thetas, 1, ell_stride, N);
    spmm_cheb<false, 1><<<spmm_blocks, 256, 0, stream>>>(
        row_start, deg, cw, tY, tX, tZ, poly, thetas, 3, ell_stride, N);
    spmm_cheb<false, 0><<<spmm_blocks, 256, 0, stream>>>(
        row_start, deg, cw, tZ, tY, tX, poly, thetas, 4, ell_stride, N);
    spmm_cheb<false, 2><<<spmm_blocks, 256, 0, stream>>>(
        row_start, deg, cw, tX, tZ, tY, poly, thetas, 5, ell_stride, N);
    spmm_cheb<false, 0><<<spmm_blocks, 256, 0, stream>>>(
        row_start, deg, cw, tY, tX, tZ, poly, thetas, 6, ell_stride, N);
    spmm_cheb<false, 3><<<spmm_blocks, 256, 0, stream>>>(
        row_start, deg, cw, tZ, tY, (bf16*)nullptr, poly, thetas, 7, ell_stride, N);

    fc2_softmax<<<(N + 255) / 256, 256, 0, stream>>>(poly, w2, b2, out, N);
}

extern "C" void kernel_launch(void* const* d_in, const int* in_sizes, int n_in,
                              void* d_out, int out_size, void* d_ws, size_t ws_size,
                              hipStream_t stream) {
    const float* x      = (const float*)d_in[0];
    const int*   erow   = (const int*)d_in[1];
    const int*   ecol   = (const int*)d_in[2];
    const float* ew     = (const float*)d_in[3];
    const float* w1     = (const float*)d_in[4];
    const float* b1     = (const float*)d_in[5];
    const float* w2     = (const float*)d_in[6];
    const float* b2     = (const float*)d_in[7];
    const float* thetas = (const float*)d_in[8];
    float* out = (float*)d_out;

    const int N = in_sizes[0] / NFEAT;
    const int E = in_sizes[1];

    const int NB   = (N + RPB - 1) >> RPB_SH;   // row buckets
    const int NBLK = (E + CH - 1) / CH;          // edge chunks

    char* ws = (char*)d_ws;
    size_t off = 0;
    auto alloc = [&](size_t bytes) -> void* {
        off = (off + 255) & ~(size_t)255;
        void* p = ws + off;
        off += bytes;
        return p;
    };

    // Shared tail: poly + 3 bf16 t buffers.
    size_t tail = (size_t)N * NHID * 4 + 3 * ((size_t)N * NHID * 2 + 256) + 4096;

    size_t need_sort = 2 * (size_t)NB * NBLK * 4 + (size_t)(NB + 1) * 4 +
                       (size_t)E * 4 + (size_t)E * 8 +           // bin_row, bin_cw
                       2 * (size_t)N * 4 +                        // deg, row_start
                       (size_t)E * 8 + tail + 8192;               // cw compact
    size_t need_ell  = (size_t)N * 4 + (size_t)N * ELLS * 8 + tail + 8192;

    if (NB <= NBMAX && need_sort <= ws_size) {
        // -------- primary: deterministic counting-sort CSR --------
        int*  cntT      = (int*)alloc((size_t)NB * NBLK * 4);
        int*  offsT     = (int*)alloc((size_t)NB * NBLK * 4);
        int*  bbase     = (int*)alloc((size_t)(NB + 1) * 4);
        int*  bin_row   = (int*)alloc((size_t)E * 4);
        int2* bin_cw    = (int2*)alloc((size_t)E * 8);
        int*  deg       = (int*)alloc((size_t)N * 4);
        int*  row_start = (int*)alloc((size_t)N * 4);
        int2* cw        = (int2*)alloc((size_t)E * 8);
        float* poly = (float*)alloc((size_t)N * NHID * 4);
        bf16*  tX   = (bf16*)alloc((size_t)N * NHID * 2);
        bf16*  tY   = (bf16*)alloc((size_t)N * NHID * 2);
        bf16*  tZ   = (bf16*)alloc((size_t)N * NHID * 2);

        s1_hist<<<NBLK, 256, 0, stream>>>(erow, cntT, E, NB, NBLK);
        s2_bases<<<1, 512, 0, stream>>>(cntT, bbase, NB, NBLK, E);
        s2_offsets<<<NB, 256, 0, stream>>>(cntT, bbase, offsT, NBLK);
        s3_bin<<<NBLK, 256, 0, stream>>>(erow, ecol, ew, offsT, bin_row, bin_cw, E, NB, NBLK);
        s4_build<<<NB, 256, 0, stream>>>(bbase, bin_row, bin_cw, deg, row_start, cw, N);
        run_pipeline(x, w1, b1, w2, b2, thetas, out, N, E,
                     row_start, deg, cw, 0, poly, tX, tY, tZ, stream);
    } else if (need_ell <= ws_size) {
        // -------- tier-2: atomic ELL --------
        int*   deg  = (int*)alloc((size_t)N * 4);
        int2*  cw   = (int2*)alloc((size_t)N * ELLS * 8);
        float* poly = (float*)alloc((size_t)N * NHID * 4);
        bf16*  tX   = (bf16*)alloc((size_t)N * NHID * 2);
        bf16*  tY   = (bf16*)alloc((size_t)N * NHID * 2);
        bf16*  tZ   = (bf16*)alloc((size_t)N * NHID * 2);

        zero_ints<<<(N + 255) / 256, 256, 0, stream>>>(deg, N);
        scatter_ell<<<(E + 255) / 256, 256, 0, stream>>>(erow, ecol, ew, deg, cw, E);
        run_pipeline(x, w1, b1, w2, b2, thetas, out, N, E,
                     nullptr, deg, cw, ELLS, poly, tX, tY, tZ, stream);
    } else {
        // -------- tier-3: compact CSR via atomics --------
        int*   deg       = (int*)alloc((size_t)(N + 1) * 4);
        int*   counter   = deg + N;
        int*   row_start = (int*)alloc((size_t)N * 4);
        int*   cursor    = (int*)alloc((size_t)N * 4);
        int2*  cw        = (int2*)alloc((size_t)E * 8);
        float* poly      = (float*)alloc((size_t)N * NHID * 4);
        bf16*  tX        = (bf16*)alloc((size_t)N * NHID * 2);
        bf16*  tY        = (bf16*)alloc((size_t)N * NHID * 2);
        bf16*  tZ        = (bf16*)alloc((size_t)N * NHID * 2);

        zero_ints<<<(N + 1 + 255) / 256, 256, 0, stream>>>(deg, N + 1);
        hist_kernel<<<(E + 255) / 256, 256, 0, stream>>>(erow, deg, E);
        assign_starts<<<(N + 255) / 256, 256, 0, stream>>>(deg, counter, row_start, cursor, N);
        scatter_compact<<<(E + 255) / 256, 256, 0, stream>>>(erow, ecol, ew, cursor, cw, E);
        run_pipeline(x, w1, b1, w2, b2, thetas, out, N, E,
                     row_start, deg, cw, 0, poly, tX, tY, tZ, stream);
    }
}